// Round 6
// baseline (1028.499 us; speedup 1.0000x reference)
//
#include <hip/hip_runtime.h>
#include <hip/hip_bf16.h>

typedef unsigned short u16;
typedef __attribute__((ext_vector_type(8))) short s16x8;
typedef __attribute__((ext_vector_type(4))) float f32x4;

#define MFMA16 __builtin_amdgcn_mfma_f32_16x16x32_bf16
#define AS1 __attribute__((address_space(1)))
#define AS3 __attribute__((address_space(3)))

__device__ __forceinline__ u16 f2bf(float f) {
    union { __hip_bfloat16 h; u16 u; } cv;
    cv.h = __float2bfloat16(f);
    return cv.u;
}
__device__ __forceinline__ float bf2f(u16 u) {
    unsigned int v = ((unsigned int)u) << 16;
    return __uint_as_float(v);
}
__device__ __forceinline__ void gll16(const u16* g, u16* l) {
    __builtin_amdgcn_global_load_lds((AS1 void*)g, (AS3 void*)l, 16, 0, 0);
}

// ---------------- fp32 -> bf16 weight convert ----------------
__global__ void cvt_kernel(const float* __restrict__ src, u16* __restrict__ dst, int n) {
    int i = (blockIdx.x * 256 + threadIdx.x) * 4;
    if (i + 3 < n) {
        float4 v = *(const float4*)&src[i];
        u16 o0 = f2bf(v.x), o1 = f2bf(v.y), o2 = f2bf(v.z), o3 = f2bf(v.w);
        ushort4 o; o.x = o0; o.y = o1; o.z = o2; o.w = o3;
        *(ushort4*)&dst[i] = o;
    }
}

// ---------------- LayerNorm (768) -> bf16 ----------------
__global__ __launch_bounds__(256) void ln_kernel(const float* __restrict__ x,
                                                 const float* __restrict__ w,
                                                 const float* __restrict__ b,
                                                 u16* __restrict__ out) {
    int tok = blockIdx.x;
    int tid = threadIdx.x;
    const float* xr = x + (size_t)tok * 768;
    float v0 = xr[tid], v1 = xr[tid + 256], v2 = xr[tid + 512];
    float s = v0 + v1 + v2;
    float s2 = v0 * v0 + v1 * v1 + v2 * v2;
    #pragma unroll
    for (int d = 1; d < 64; d <<= 1) { s += __shfl_xor(s, d); s2 += __shfl_xor(s2, d); }
    __shared__ float red[8];
    int wv = tid >> 6, l = tid & 63;
    if (l == 0) { red[wv] = s; red[4 + wv] = s2; }
    __syncthreads();
    s = red[0] + red[1] + red[2] + red[3];
    s2 = red[4] + red[5] + red[6] + red[7];
    float mu = s * (1.0f / 768.0f);
    float var = s2 * (1.0f / 768.0f) - mu * mu;
    float rs = rsqrtf(var + 1e-6f);
    u16* orow = out + (size_t)tok * 768;
    orow[tid]       = f2bf((v0 - mu) * rs * w[tid]       + b[tid]);
    orow[tid + 256] = f2bf((v1 - mu) * rs * w[tid + 256] + b[tid + 256]);
    orow[tid + 512] = f2bf((v2 - mu) * rs * w[tid + 512] + b[tid + 512]);
}

// ---------------- GEMM: C[M,N] = A[M,K] * Bw[N,K]^T (+epilogue) ----------------
// 256x256 tile, BK=64, 8 waves (512 thr), 2-phase double-buffered LDS (128 KB).
// Swizzled 16B slots (XOR over 8 slots per row) -> conflict-free ds_read_b128.
// EPI 0: out bf16, no bias.  EPI 1: out fp32 = res + acc + bias.  EPI 2: out bf16 = gelu(acc+bias).
template<int EPI>
__global__ __launch_bounds__(512, 2) void gemm_bt(const u16* __restrict__ A,
                                                  const u16* __restrict__ Bw,
                                                  const float* __restrict__ bias,
                                                  const float* __restrict__ res,
                                                  float* __restrict__ outF,
                                                  u16* __restrict__ outU,
                                                  int M, int N, int K) {
    // u16 units: buf0 A [0,16384), buf0 B [16384,32768), buf1 at +32768. 128 KB total.
    __shared__ u16 lds[65536];
    const int tid = threadIdx.x;
    const int l = tid & 63, w = tid >> 6;
    const int wr = w >> 2, wc = w & 3;       // wave tile: rows wr*128(+128), cols wc*64(+64)
    const int g = l >> 4, c = l & 15;
    const int m0 = blockIdx.y * 256, n0 = blockIdx.x * 256;

    f32x4 zf = {0.f, 0.f, 0.f, 0.f};
    f32x4 acc[8][4];
    #pragma unroll
    for (int m = 0; m < 8; ++m)
        #pragma unroll
        for (int n = 0; n < 4; ++n) acc[m][n] = zf;

    // staging: 2048 16B-chunks per matrix per tile; thread handles chunks i*512+tid.
    // chunk fs -> row r=fs>>3, physical slot sl=fs&7 holds logical k-group gk=sl^((r>>1)&7)
    const u16* aP[4]; const u16* bP[4]; int dOff[4];
    #pragma unroll
    for (int i = 0; i < 4; ++i) {
        int fs = i * 512 + tid;
        int r = fs >> 3;
        int gk = (fs & 7) ^ ((r >> 1) & 7);
        int ra = m0 + r; if (ra > M - 1) ra = M - 1;
        aP[i] = A + (size_t)ra * K + gk * 8;
        bP[i] = Bw + (size_t)(n0 + r) * K + gk * 8;
        dOff[i] = fs * 8;
    }

    // fragment read offsets (u16 units). swizzle reduces to swz=(c>>1)&7 (row-bits cancel).
    const int swz = (c >> 1) & 7;
    int aRow[8], bRow[4], slotU[2];
    #pragma unroll
    for (int m = 0; m < 8; ++m) aRow[m] = (wr * 128 + m * 16 + c) * 64;
    #pragma unroll
    for (int n = 0; n < 4; ++n) bRow[n] = 16384 + (wc * 64 + n * 16 + c) * 64;
    slotU[0] = ((0 + g) ^ swz) * 8;
    slotU[1] = ((4 + g) ^ swz) * 8;

#define STAGE(t, bb) { \
        const int k0_ = (t) * 64; \
        _Pragma("unroll") \
        for (int i = 0; i < 4; ++i) gll16(aP[i] + k0_, &lds[(bb) + dOff[i]]); \
        _Pragma("unroll") \
        for (int i = 0; i < 4; ++i) gll16(bP[i] + k0_, &lds[(bb) + 16384 + dOff[i]]); \
    }
#define COMPUTE(bb) { \
        _Pragma("unroll") \
        for (int kk = 0; kk < 2; ++kk) { \
            s16x8 af[8], bf[4]; \
            _Pragma("unroll") \
            for (int m = 0; m < 8; ++m) af[m] = *(const s16x8*)&lds[(bb) + aRow[m] + slotU[kk]]; \
            _Pragma("unroll") \
            for (int n = 0; n < 4; ++n) bf[n] = *(const s16x8*)&lds[(bb) + bRow[n] + slotU[kk]]; \
            _Pragma("unroll") \
            for (int m = 0; m < 8; ++m) \
                _Pragma("unroll") \
                for (int n = 0; n < 4; ++n) \
                    acc[m][n] = MFMA16(af[m], bf[n], acc[m][n], 0, 0, 0); \
        } \
    }

    const int nt = K >> 6;  // 12 or 48 (even)

    STAGE(0, 0);
    __syncthreads();

    #pragma unroll 1
    for (int t = 0; t < nt; t += 2) {
        STAGE(t + 1, 32768);
        COMPUTE(0);
        __syncthreads();
        if (t + 2 < nt) STAGE(t + 2, 0);
        COMPUTE(32768);
        __syncthreads();
    }

#undef STAGE
#undef COMPUTE

    // epilogue
    #pragma unroll
    for (int n = 0; n < 4; ++n) {
        int col = n0 + wc * 64 + n * 16 + c;
        float bv = (EPI >= 1) ? bias[col] : 0.0f;
        #pragma unroll
        for (int m = 0; m < 8; ++m) {
            int rowb = m0 + wr * 128 + m * 16 + g * 4;
            #pragma unroll
            for (int j = 0; j < 4; ++j) {
                int row = rowb + j;
                if (row < M) {
                    float v = acc[m][n][j];
                    size_t idx = (size_t)row * N + col;
                    if (EPI == 0) {
                        outU[idx] = f2bf(v);
                    } else if (EPI == 1) {
                        outF[idx] = res[idx] + v + bv;
                    } else {
                        // fast GELU: t * sigmoid(1.5958t + 0.07135t^3); |err| < 1e-3
                        float tt = v + bv;
                        float sg = __expf(-(1.59576912f * tt + 0.0713548162f * tt * tt * tt));
                        float rr = tt * __builtin_amdgcn_rcpf(1.0f + sg);
                        outU[idx] = f2bf(rr);
                    }
                }
            }
        }
    }
}

// ---------------- cls global attention: split-K phase 1 ----------------
// grid = B*H*17; each block does a 128-key chunk, writes partial (m, s, o[64])
__global__ __launch_bounds__(256) void cls_part(const u16* __restrict__ qkv,
                                                float* __restrict__ part) {
    int bid = blockIdx.x;
    int ch = bid % 17;
    int hh = (bid / 17) % 12;
    int b = bid / (17 * 12);
    int tid = threadIdx.x, l = tid & 63, w = tid >> 6;
    size_t base = (size_t)b * 2049 * 2304;
    float qv = bf2f(qkv[base + hh * 64 + l]);
    __shared__ float sc[128];
    __shared__ float red[8];
    __shared__ float pv[4][64];
    int j0 = ch * 128;
    int nk = 2049 - j0; if (nk > 128) nk = 128;

    for (int jj = w; jj < nk; jj += 4) {
        float kv = bf2f(qkv[base + (size_t)(j0 + jj) * 2304 + 768 + hh * 64 + l]);
        float p = qv * kv;
        p += __shfl_xor(p, 1);  p += __shfl_xor(p, 2);  p += __shfl_xor(p, 4);
        p += __shfl_xor(p, 8);  p += __shfl_xor(p, 16); p += __shfl_xor(p, 32);
        if (l == 0) sc[jj] = p * 0.125f;
    }
    __syncthreads();
    float mx = -1e30f;
    for (int jj = tid; jj < nk; jj += 256) mx = fmaxf(mx, sc[jj]);
    #pragma unroll
    for (int d = 1; d < 64; d <<= 1) mx = fmaxf(mx, __shfl_xor(mx, d));
    if (l == 0) red[w] = mx;
    __syncthreads();
    mx = fmaxf(fmaxf(red[0], red[1]), fmaxf(red[2], red[3]));
    float sum = 0.0f;
    for (int jj = tid; jj < nk; jj += 256) {
        float p = __expf(sc[jj] - mx);
        sc[jj] = p;
        sum += p;
    }
    #pragma unroll
    for (int d = 1; d < 64; d <<= 1) sum += __shfl_xor(sum, d);
    if (l == 0) red[4 + w] = sum;
    __syncthreads();
    sum = red[4] + red[5] + red[6] + red[7];

    // PV partial: lane = dim, wave strides over keys
    float acc = 0.0f;
    for (int jj = w; jj < nk; jj += 4)
        acc += sc[jj] * bf2f(qkv[base + (size_t)(j0 + jj) * 2304 + 1536 + hh * 64 + l]);
    pv[w][l] = acc;
    __syncthreads();
    if (tid < 64) {
        float o = pv[0][tid] + pv[1][tid] + pv[2][tid] + pv[3][tid];
        float* rec = part + ((size_t)(b * 12 + hh) * 17 + ch) * 66;
        rec[2 + tid] = o;
        if (tid == 0) { rec[0] = mx; rec[1] = sum; }
    }
}

// ---------------- cls split-K phase 2: merge 17 partials, write y row 0 ----------------
// grid = B*H = 96, block 64
__global__ __launch_bounds__(64) void cls_red(const float* __restrict__ part,
                                              const u16* __restrict__ h1,
                                              u16* __restrict__ y) {
    int bid = blockIdx.x;
    int hh = bid % 12, b = bid / 12;
    int l = threadIdx.x;
    const float* recs = part + (size_t)bid * 17 * 66;
    float M = -1e30f;
    #pragma unroll
    for (int i = 0; i < 17; ++i) M = fmaxf(M, recs[i * 66]);
    float den = 0.0f, o = 0.0f;
    #pragma unroll
    for (int i = 0; i < 17; ++i) {
        float scl = __expf(recs[i * 66] - M);
        den += scl * recs[i * 66 + 1];
        o += scl * recs[i * 66 + 2 + l];
    }
    o /= den;
    float r = bf2f(h1[(size_t)b * 2049 * 768 + hh * 64 + l]);
    y[(size_t)b * 1573632 + hh * 64 + l] = f2bf(o + r);
}

// ---------------- qkv_c = cls @ qkv_w^T  (tiny GEMM) ----------------
// grid = 18432/4, wave per output element
__global__ __launch_bounds__(256) void qkvc_gemm(const u16* __restrict__ y,
                                                 const u16* __restrict__ wq,
                                                 u16* __restrict__ qkvc) {
    int tid = threadIdx.x, l = tid & 63, w = tid >> 6;
    int oi = blockIdx.x * 4 + w;  // 0..18431
    int b = oi / 2304, n = oi % 2304;
    float acc = 0.0f;
    #pragma unroll
    for (int i = 0; i < 12; ++i) {
        int k = i * 64 + l;
        acc += bf2f(y[(size_t)b * 1573632 + k]) * bf2f(wq[(size_t)n * 768 + k]);
    }
    #pragma unroll
    for (int d = 1; d < 64; d <<= 1) acc += __shfl_xor(acc, d);
    if (l == 0) qkvc[b * 2304 + n] = f2bf(acc);
}

// ---------------- branch attention (flash, MFMA) ----------------
// grid = B*H*NB*4 = 1536; 4 waves x 32 q-rows.  17 key tiles: 16x32 regular + cls.
__global__ __launch_bounds__(256, 2) void battn(const u16* __restrict__ qkv,
                                                const u16* __restrict__ qkvc,
                                                u16* __restrict__ y) {
    __shared__ u16 Vt[64 * 40];      // V^T [d][key] padded rows (80B)
    __shared__ u16 Pl[4][32 * 40];   // per-wave P [q][key] padded rows
    int bid = blockIdx.x;
    int quarter = bid & 3, nb = (bid >> 2) & 3, h = (bid >> 4) % 12, b = bid / 192;
    int tid = threadIdx.x, l = tid & 63, w = tid >> 6, g = l >> 4, c = l & 15;
    int qbase = quarter * 128 + w * 32;
    size_t tokbase = (size_t)b * 2049 + 1 + (size_t)nb * 512;

    s16x8 qf[2][2];
    #pragma unroll
    for (int qm = 0; qm < 2; ++qm)
        #pragma unroll
        for (int kc = 0; kc < 2; ++kc)
            qf[qm][kc] = *(const s16x8*)&qkv[(tokbase + qbase + qm * 16 + c) * 2304 + h * 64 + kc * 32 + g * 8];

    f32x4 zf = {0.f, 0.f, 0.f, 0.f};
    f32x4 o[2][4];
    float mst[2][4], lst[2][4];
    #pragma unroll
    for (int qm = 0; qm < 2; ++qm) {
        #pragma unroll
        for (int dn = 0; dn < 4; ++dn) o[qm][dn] = zf;
        #pragma unroll
        for (int j = 0; j < 4; ++j) { mst[qm][j] = -1e30f; lst[qm][j] = 0.0f; }
    }

    for (int t = 0; t <= 16; ++t) {
        __syncthreads();  // protect previous Vt reads
        if (t < 16) {
            int key = tid & 31, dg = tid >> 5;
            s16x8 vv = *(const s16x8*)&qkv[(tokbase + t * 32 + key) * 2304 + 1536 + h * 64 + dg * 8];
            #pragma unroll
            for (int i = 0; i < 8; ++i) Vt[(dg * 8 + i) * 40 + key] = (u16)vv[i];
        } else {
            for (int i = tid; i < 2560; i += 256) Vt[i] = 0;
            __syncthreads();
            if (tid < 64) Vt[tid * 40] = qkvc[b * 2304 + 1536 + h * 64 + tid];
        }
        __syncthreads();  // Vt ready

        f32x4 sfr[2][2];
        #pragma unroll
        for (int qm = 0; qm < 2; ++qm) { sfr[qm][0] = zf; sfr[qm][1] = zf; }

        if (t < 16) {
            #pragma unroll
            for (int kn = 0; kn < 2; ++kn)
                #pragma unroll
                for (int kc = 0; kc < 2; ++kc) {
                    s16x8 bk = *(const s16x8*)&qkv[(tokbase + t * 32 + kn * 16 + c) * 2304 + 768 + h * 64 + kc * 32 + g * 8];
                    #pragma unroll
                    for (int qm = 0; qm < 2; ++qm)
                        sfr[qm][kn] = MFMA16(qf[qm][kc], bk, sfr[qm][kn], 0, 0, 0);
                }
        } else {
            #pragma unroll
            for (int kc = 0; kc < 2; ++kc) {
                s16x8 bk = {0, 0, 0, 0, 0, 0, 0, 0};
                if (c == 0) bk = *(const s16x8*)&qkvc[b * 2304 + 768 + h * 64 + kc * 32 + g * 8];
                #pragma unroll
                for (int qm = 0; qm < 2; ++qm)
                    sfr[qm][0] = MFMA16(qf[qm][kc], bk, sfr[qm][0], 0, 0, 0);
            }
        }

        #pragma unroll
        for (int qm = 0; qm < 2; ++qm) {
            #pragma unroll
            for (int j = 0; j < 4; ++j) {
                float v0 = sfr[qm][0][j] * 0.125f;
                float v1 = (t < 16) ? sfr[qm][1][j] * 0.125f : -1e30f;
                if (t == 16 && c != 0) v0 = -1e30f;
                float tm = fmaxf(v0, v1);
                tm = fmaxf(tm, __shfl_xor(tm, 1));
                tm = fmaxf(tm, __shfl_xor(tm, 2));
                tm = fmaxf(tm, __shfl_xor(tm, 4));
                tm = fmaxf(tm, __shfl_xor(tm, 8));
                float mo = mst[qm][j];
                float mn = fmaxf(mo, tm);
                float scl = __expf(mo - mn);
                float p0 = __expf(v0 - mn);
                float p1 = __expf(v1 - mn);
                float ps = p0 + p1;
                ps += __shfl_xor(ps, 1); ps += __shfl_xor(ps, 2);
                ps += __shfl_xor(ps, 4); ps += __shfl_xor(ps, 8);
                lst[qm][j] = lst[qm][j] * scl + ps;
                mst[qm][j] = mn;
                #pragma unroll
                for (int dn = 0; dn < 4; ++dn) o[qm][dn][j] *= scl;
                int q = qm * 16 + g * 4 + j;
                Pl[w][q * 40 + c] = f2bf(p0);
                Pl[w][q * 40 + 16 + c] = f2bf(p1);
            }
        }

        // PV
        s16x8 pa[2], vb[4];
        #pragma unroll
        for (int qm = 0; qm < 2; ++qm) pa[qm] = *(const s16x8*)&Pl[w][(qm * 16 + c) * 40 + g * 8];
        #pragma unroll
        for (int dn = 0; dn < 4; ++dn) vb[dn] = *(const s16x8*)&Vt[(dn * 16 + c) * 40 + g * 8];
        #pragma unroll
        for (int qm = 0; qm < 2; ++qm)
            #pragma unroll
            for (int dn = 0; dn < 4; ++dn)
                o[qm][dn] = MFMA16(pa[qm], vb[dn], o[qm][dn], 0, 0, 0);
    }

    // scattered store (raw row-major reinterpretation layout)
    size_t ybase = (size_t)b * 1573632 + 768 + (size_t)nb * 393216 + (size_t)h * 32768;
    #pragma unroll
    for (int qm = 0; qm < 2; ++qm)
        #pragma unroll
        for (int dn = 0; dn < 4; ++dn)
            #pragma unroll
            for (int j = 0; j < 4; ++j) {
                int q = qbase + qm * 16 + g * 4 + j;
                int d = dn * 16 + c;
                y[ybase + (size_t)q * 64 + d] = f2bf(o[qm][dn][j] / lst[qm][j]);
            }
}

// ---------------- launch ----------------
extern "C" void kernel_launch(void* const* d_in, const int* in_sizes, int n_in,
                              void* d_out, int out_size, void* d_ws, size_t ws_size,
                              hipStream_t stream) {
    const float* x      = (const float*)d_in[0];
    const float* ln1_w  = (const float*)d_in[1];
    const float* ln1_b  = (const float*)d_in[2];
    const float* qkv_w  = (const float*)d_in[3];
    const float* proj_w = (const float*)d_in[4];
    const float* proj_b = (const float*)d_in[5];
    const float* ln2_w  = (const float*)d_in[6];
    const float* ln2_b  = (const float*)d_in[7];
    const float* fc1_w  = (const float*)d_in[8];
    const float* fc1_b  = (const float*)d_in[9];
    const float* fc2_w  = (const float*)d_in[10];
    const float* fc2_b  = (const float*)d_in[11];
    float* out = (float*)d_out;
    char* ws = (char*)d_ws;

    // ws layout (bytes); gbuf overlays [h1,qkv]; cls partials overlay x2 (temporally disjoint).
    u16* Wq   = (u16*)(ws + 0);
    u16* Wp   = (u16*)(ws + 3538944);
    u16* Wf1  = (u16*)(ws + 4718592);
    u16* Wf2  = (u16*)(ws + 9437184);
    u16* h1   = (u16*)(ws + 14155776);
    u16* qkv  = (u16*)(ws + 39333888);
    u16* yb   = (u16*)(ws + 114868224);
    float* x2 = (float*)(ws + 140046336);
    u16* h2   = (u16*)(ws + 190402560);
    u16* qkvc = (u16*)(ws + 215580672);
    u16* gbuf = (u16*)(ws + 14155776);   // overlay
    float* part = (float*)(ws + 140046336);  // overlay on x2 (free until proj gemm)

    cvt_kernel<<<1728, 256, 0, stream>>>(qkv_w, Wq, 1769472);
    cvt_kernel<<<576,  256, 0, stream>>>(proj_w, Wp, 589824);
    cvt_kernel<<<2304, 256, 0, stream>>>(fc1_w, Wf1, 2359296);
    cvt_kernel<<<2304, 256, 0, stream>>>(fc2_w, Wf2, 2359296);

    ln_kernel<<<16392, 256, 0, stream>>>(x, ln1_w, ln1_b, h1);
    gemm_bt<0><<<dim3(9, 65), 512, 0, stream>>>(h1, Wq, nullptr, nullptr, nullptr, qkv, 16392, 2304, 768);
    cls_part<<<1632, 256, 0, stream>>>(qkv, part);
    cls_red<<<96, 64, 0, stream>>>(part, h1, yb);
    qkvc_gemm<<<4608, 256, 0, stream>>>(yb, Wq, qkvc);
    battn<<<1536, 256, 0, stream>>>(qkv, qkvc, yb);
    gemm_bt<1><<<dim3(3, 65), 512, 0, stream>>>(yb, Wp, proj_b, x, x2, nullptr, 16392, 768, 768);
    ln_kernel<<<16392, 256, 0, stream>>>(x2, ln2_w, ln2_b, h2);
    gemm_bt<2><<<dim3(12, 65), 512, 0, stream>>>(h2, Wf1, fc1_b, nullptr, nullptr, gbuf, 16392, 3072, 768);
    gemm_bt<1><<<dim3(3, 65), 512, 0, stream>>>(gbuf, Wf2, fc2_b, x2, out, nullptr, 16392, 768, 3072);
}

// Round 7
// 777.547 us; speedup vs baseline: 1.3227x; 1.3227x over previous
//
#include <hip/hip_runtime.h>
#include <hip/hip_bf16.h>

typedef unsigned short u16;
typedef __attribute__((ext_vector_type(8))) short s16x8;
typedef __attribute__((ext_vector_type(4))) float f32x4;

#define MFMA16 __builtin_amdgcn_mfma_f32_16x16x32_bf16
#define AS1 __attribute__((address_space(1)))
#define AS3 __attribute__((address_space(3)))

__device__ __forceinline__ u16 f2bf(float f) {
    union { __hip_bfloat16 h; u16 u; } cv;
    cv.h = __float2bfloat16(f);
    return cv.u;
}
__device__ __forceinline__ float bf2f(u16 u) {
    unsigned int v = ((unsigned int)u) << 16;
    return __uint_as_float(v);
}
__device__ __forceinline__ void gll16(const u16* g, u16* l) {
    __builtin_amdgcn_global_load_lds((AS1 void*)g, (AS3 void*)l, 16, 0, 0);
}

// ---------------- fp32 -> bf16 weight convert ----------------
__global__ void cvt_kernel(const float* __restrict__ src, u16* __restrict__ dst, int n) {
    int i = (blockIdx.x * 256 + threadIdx.x) * 4;
    if (i + 3 < n) {
        float4 v = *(const float4*)&src[i];
        u16 o0 = f2bf(v.x), o1 = f2bf(v.y), o2 = f2bf(v.z), o3 = f2bf(v.w);
        ushort4 o; o.x = o0; o.y = o1; o.z = o2; o.w = o3;
        *(ushort4*)&dst[i] = o;
    }
}

// ---------------- LayerNorm (768) -> bf16 ----------------
__global__ __launch_bounds__(256) void ln_kernel(const float* __restrict__ x,
                                                 const float* __restrict__ w,
                                                 const float* __restrict__ b,
                                                 u16* __restrict__ out) {
    int tok = blockIdx.x;
    int tid = threadIdx.x;
    const float* xr = x + (size_t)tok * 768;
    float v0 = xr[tid], v1 = xr[tid + 256], v2 = xr[tid + 512];
    float s = v0 + v1 + v2;
    float s2 = v0 * v0 + v1 * v1 + v2 * v2;
    #pragma unroll
    for (int d = 1; d < 64; d <<= 1) { s += __shfl_xor(s, d); s2 += __shfl_xor(s2, d); }
    __shared__ float red[8];
    int wv = tid >> 6, l = tid & 63;
    if (l == 0) { red[wv] = s; red[4 + wv] = s2; }
    __syncthreads();
    s = red[0] + red[1] + red[2] + red[3];
    s2 = red[4] + red[5] + red[6] + red[7];
    float mu = s * (1.0f / 768.0f);
    float var = s2 * (1.0f / 768.0f) - mu * mu;
    float rs = rsqrtf(var + 1e-6f);
    u16* orow = out + (size_t)tok * 768;
    orow[tid]       = f2bf((v0 - mu) * rs * w[tid]       + b[tid]);
    orow[tid + 256] = f2bf((v1 - mu) * rs * w[tid + 256] + b[tid + 256]);
    orow[tid + 512] = f2bf((v2 - mu) * rs * w[tid + 512] + b[tid + 512]);
}

// ---------------- GEMM: C[M,N] = A[M,K] * Bw[N,K]^T (+epilogue) ----------------
// 256x256 tile, BK=32, 8 waves (512 thr), 3-buffer LDS ring (96 KB) with
// counted vmcnt (T4): per step {s_waitcnt vmcnt(4); s_barrier}; loads for the
// next stage stay in flight across the barrier, never drained to 0 mid-loop.
// Swizzled 16B slots (XOR over 4 slots per row) -> 2-way banks only (free).
// EPI 0: out bf16, no bias.  EPI 1: out fp32 = res + acc + bias.  EPI 2: out bf16 = gelu(acc+bias).
template<int EPI>
__global__ __launch_bounds__(512, 2) void gemm_bt(const u16* __restrict__ A,
                                                  const u16* __restrict__ Bw,
                                                  const float* __restrict__ bias,
                                                  const float* __restrict__ res,
                                                  float* __restrict__ outF,
                                                  u16* __restrict__ outU,
                                                  int M, int N, int K) {
    // u16 units: buf k at k*16384; within buf: A [0,8192), B [8192,16384). 96 KB total.
    __shared__ u16 lds[49152];
    const int tid = threadIdx.x;
    const int l = tid & 63, w = tid >> 6;
    const int wr = w >> 2, wc = w & 3;       // wave tile: rows wr*128(+128), cols wc*64(+64)
    const int g = l >> 4, c = l & 15;
    const int m0 = blockIdx.y * 256, n0 = blockIdx.x * 256;

    f32x4 zf = {0.f, 0.f, 0.f, 0.f};
    f32x4 acc[8][4];
    #pragma unroll
    for (int m = 0; m < 8; ++m)
        #pragma unroll
        for (int n = 0; n < 4; ++n) acc[m][n] = zf;

    // staging: per tile, A = 1024 16B-chunks, B = 1024; thread does 2 of each.
    // chunk fs -> row r=fs>>2, physical slot sl=fs&3 holds logical k-group gk=sl^((r>>1)&3)
    const u16* aP[2]; const u16* bP[2]; int dOff[2];
    #pragma unroll
    for (int i = 0; i < 2; ++i) {
        int fs = i * 512 + tid;
        int r = fs >> 2;
        int gk = (fs & 3) ^ ((r >> 1) & 3);
        int ra = m0 + r; if (ra > M - 1) ra = M - 1;
        aP[i] = A + (size_t)ra * K + gk * 8;
        bP[i] = Bw + (size_t)(n0 + r) * K + gk * 8;
        dOff[i] = fs * 8;
    }

    // fragment read offsets (u16 units); physical slot = g ^ ((c>>1)&3) (row-bits cancel)
    const int slotU = ((g ^ ((c >> 1) & 3))) * 8;
    int aRow[8], bRow[4];
    #pragma unroll
    for (int m = 0; m < 8; ++m) aRow[m] = (wr * 128 + m * 16 + c) * 32 + slotU;
    #pragma unroll
    for (int n = 0; n < 4; ++n) bRow[n] = 8192 + (wc * 64 + n * 16 + c) * 32 + slotU;

#define STAGE(t, bb) { \
        const int k0_ = (t) << 5; \
        gll16(aP[0] + k0_, &lds[(bb) + dOff[0]]); \
        gll16(aP[1] + k0_, &lds[(bb) + dOff[1]]); \
        gll16(bP[0] + k0_, &lds[(bb) + 8192 + dOff[0]]); \
        gll16(bP[1] + k0_, &lds[(bb) + 8192 + dOff[1]]); \
    }
#define COMPUTE(bb) { \
        s16x8 af[8], bf[4]; \
        _Pragma("unroll") \
        for (int m = 0; m < 8; ++m) af[m] = *(const s16x8*)&lds[(bb) + aRow[m]]; \
        _Pragma("unroll") \
        for (int n = 0; n < 4; ++n) bf[n] = *(const s16x8*)&lds[(bb) + bRow[n]]; \
        _Pragma("unroll") \
        for (int m = 0; m < 8; ++m) \
            _Pragma("unroll") \
            for (int n = 0; n < 4; ++n) \
                acc[m][n] = MFMA16(af[m], bf[n], acc[m][n], 0, 0, 0); \
    }
#define WAITBAR4 asm volatile("s_waitcnt vmcnt(4)\n\ts_barrier" ::: "memory");
#define WAITBAR0 asm volatile("s_waitcnt vmcnt(0)\n\ts_barrier" ::: "memory");

    const int nt = K >> 5;  // 24 or 96 (divisible by 3, >= 6)

    STAGE(0, 0);
    STAGE(1, 16384);

    int t = 0;
    #pragma unroll 1
    for (int it = 0; it < nt / 3 - 1; ++it) {
        WAITBAR4; STAGE(t + 2, 32768); COMPUTE(0);
        WAITBAR4; STAGE(t + 3, 0);     COMPUTE(16384);
        WAITBAR4; STAGE(t + 4, 16384); COMPUTE(32768);
        t += 3;
    }
    // peeled last group (tiles nt-3 .. nt-1)
    WAITBAR4; STAGE(t + 2, 32768); COMPUTE(0);
    WAITBAR4;                      COMPUTE(16384);
    WAITBAR0;                      COMPUTE(32768);

#undef STAGE
#undef COMPUTE
#undef WAITBAR4
#undef WAITBAR0

    // epilogue
    #pragma unroll
    for (int n = 0; n < 4; ++n) {
        int col = n0 + wc * 64 + n * 16 + c;
        float bv = (EPI >= 1) ? bias[col] : 0.0f;
        #pragma unroll
        for (int m = 0; m < 8; ++m) {
            int rowb = m0 + wr * 128 + m * 16 + g * 4;
            #pragma unroll
            for (int j = 0; j < 4; ++j) {
                int row = rowb + j;
                if (row < M) {
                    float v = acc[m][n][j];
                    size_t idx = (size_t)row * N + col;
                    if (EPI == 0) {
                        outU[idx] = f2bf(v);
                    } else if (EPI == 1) {
                        outF[idx] = res[idx] + v + bv;
                    } else {
                        // fast GELU: t * sigmoid(1.5958t + 0.07135t^3); |err| < 1e-3
                        float tt = v + bv;
                        float sg = __expf(-(1.59576912f * tt + 0.0713548162f * tt * tt * tt));
                        float rr = tt * __builtin_amdgcn_rcpf(1.0f + sg);
                        outU[idx] = f2bf(rr);
                    }
                }
            }
        }
    }
}

// ---------------- cls global attention: split-K phase 1 ----------------
// grid = B*H*17; each block does a 128-key chunk, writes partial (m, s, o[64])
__global__ __launch_bounds__(256) void cls_part(const u16* __restrict__ qkv,
                                                float* __restrict__ part) {
    int bid = blockIdx.x;
    int ch = bid % 17;
    int hh = (bid / 17) % 12;
    int b = bid / (17 * 12);
    int tid = threadIdx.x, l = tid & 63, w = tid >> 6;
    size_t base = (size_t)b * 2049 * 2304;
    float qv = bf2f(qkv[base + hh * 64 + l]);
    __shared__ float sc[128];
    __shared__ float red[8];
    __shared__ float pv[4][64];
    int j0 = ch * 128;
    int nk = 2049 - j0; if (nk > 128) nk = 128;

    for (int jj = w; jj < nk; jj += 4) {
        float kv = bf2f(qkv[base + (size_t)(j0 + jj) * 2304 + 768 + hh * 64 + l]);
        float p = qv * kv;
        p += __shfl_xor(p, 1);  p += __shfl_xor(p, 2);  p += __shfl_xor(p, 4);
        p += __shfl_xor(p, 8);  p += __shfl_xor(p, 16); p += __shfl_xor(p, 32);
        if (l == 0) sc[jj] = p * 0.125f;
    }
    __syncthreads();
    float mx = -1e30f;
    for (int jj = tid; jj < nk; jj += 256) mx = fmaxf(mx, sc[jj]);
    #pragma unroll
    for (int d = 1; d < 64; d <<= 1) mx = fmaxf(mx, __shfl_xor(mx, d));
    if (l == 0) red[w] = mx;
    __syncthreads();
    mx = fmaxf(fmaxf(red[0], red[1]), fmaxf(red[2], red[3]));
    float sum = 0.0f;
    for (int jj = tid; jj < nk; jj += 256) {
        float p = __expf(sc[jj] - mx);
        sc[jj] = p;
        sum += p;
    }
    #pragma unroll
    for (int d = 1; d < 64; d <<= 1) sum += __shfl_xor(sum, d);
    if (l == 0) red[4 + w] = sum;
    __syncthreads();
    sum = red[4] + red[5] + red[6] + red[7];

    // PV partial: lane = dim, wave strides over keys
    float acc = 0.0f;
    for (int jj = w; jj < nk; jj += 4)
        acc += sc[jj] * bf2f(qkv[base + (size_t)(j0 + jj) * 2304 + 1536 + hh * 64 + l]);
    pv[w][l] = acc;
    __syncthreads();
    if (tid < 64) {
        float o = pv[0][tid] + pv[1][tid] + pv[2][tid] + pv[3][tid];
        float* rec = part + ((size_t)(b * 12 + hh) * 17 + ch) * 66;
        rec[2 + tid] = o;
        if (tid == 0) { rec[0] = mx; rec[1] = sum; }
    }
}

// ---------------- cls split-K phase 2: merge 17 partials, write y row 0 ----------------
// grid = B*H = 96, block 64
__global__ __launch_bounds__(64) void cls_red(const float* __restrict__ part,
                                              const u16* __restrict__ h1,
                                              u16* __restrict__ y) {
    int bid = blockIdx.x;
    int hh = bid % 12, b = bid / 12;
    int l = threadIdx.x;
    const float* recs = part + (size_t)bid * 17 * 66;
    float M = -1e30f;
    #pragma unroll
    for (int i = 0; i < 17; ++i) M = fmaxf(M, recs[i * 66]);
    float den = 0.0f, o = 0.0f;
    #pragma unroll
    for (int i = 0; i < 17; ++i) {
        float scl = __expf(recs[i * 66] - M);
        den += scl * recs[i * 66 + 1];
        o += scl * recs[i * 66 + 2 + l];
    }
    o /= den;
    float r = bf2f(h1[(size_t)b * 2049 * 768 + hh * 64 + l]);
    y[(size_t)b * 1573632 + hh * 64 + l] = f2bf(o + r);
}

// ---------------- qkv_c = cls @ qkv_w^T  (tiny GEMM) ----------------
// grid = 18432/4, wave per output element
__global__ __launch_bounds__(256) void qkvc_gemm(const u16* __restrict__ y,
                                                 const u16* __restrict__ wq,
                                                 u16* __restrict__ qkvc) {
    int tid = threadIdx.x, l = tid & 63, w = tid >> 6;
    int oi = blockIdx.x * 4 + w;  // 0..18431
    int b = oi / 2304, n = oi % 2304;
    float acc = 0.0f;
    #pragma unroll
    for (int i = 0; i < 12; ++i) {
        int k = i * 64 + l;
        acc += bf2f(y[(size_t)b * 1573632 + k]) * bf2f(wq[(size_t)n * 768 + k]);
    }
    #pragma unroll
    for (int d = 1; d < 64; d <<= 1) acc += __shfl_xor(acc, d);
    if (l == 0) qkvc[b * 2304 + n] = f2bf(acc);
}

// ---------------- branch attention (flash, MFMA) ----------------
// grid = B*H*NB*4 = 1536; 4 waves x 32 q-rows.  17 key tiles: 16x32 regular + cls.
__global__ __launch_bounds__(256, 2) void battn(const u16* __restrict__ qkv,
                                                const u16* __restrict__ qkvc,
                                                u16* __restrict__ y) {
    __shared__ u16 Vt[64 * 40];      // V^T [d][key] padded rows (80B)
    __shared__ u16 Pl[4][32 * 40];   // per-wave P [q][key] padded rows
    int bid = blockIdx.x;
    int quarter = bid & 3, nb = (bid >> 2) & 3, h = (bid >> 4) % 12, b = bid / 192;
    int tid = threadIdx.x, l = tid & 63, w = tid >> 6, g = l >> 4, c = l & 15;
    int qbase = quarter * 128 + w * 32;
    size_t tokbase = (size_t)b * 2049 + 1 + (size_t)nb * 512;

    s16x8 qf[2][2];
    #pragma unroll
    for (int qm = 0; qm < 2; ++qm)
        #pragma unroll
        for (int kc = 0; kc < 2; ++kc)
            qf[qm][kc] = *(const s16x8*)&qkv[(tokbase + qbase + qm * 16 + c) * 2304 + h * 64 + kc * 32 + g * 8];

    f32x4 zf = {0.f, 0.f, 0.f, 0.f};
    f32x4 o[2][4];
    float mst[2][4], lst[2][4];
    #pragma unroll
    for (int qm = 0; qm < 2; ++qm) {
        #pragma unroll
        for (int dn = 0; dn < 4; ++dn) o[qm][dn] = zf;
        #pragma unroll
        for (int j = 0; j < 4; ++j) { mst[qm][j] = -1e30f; lst[qm][j] = 0.0f; }
    }

    for (int t = 0; t <= 16; ++t) {
        __syncthreads();  // protect previous Vt reads
        if (t < 16) {
            int key = tid & 31, dg = tid >> 5;
            s16x8 vv = *(const s16x8*)&qkv[(tokbase + t * 32 + key) * 2304 + 1536 + h * 64 + dg * 8];
            #pragma unroll
            for (int i = 0; i < 8; ++i) Vt[(dg * 8 + i) * 40 + key] = (u16)vv[i];
        } else {
            for (int i = tid; i < 2560; i += 256) Vt[i] = 0;
            __syncthreads();
            if (tid < 64) Vt[tid * 40] = qkvc[b * 2304 + 1536 + h * 64 + tid];
        }
        __syncthreads();  // Vt ready

        f32x4 sfr[2][2];
        #pragma unroll
        for (int qm = 0; qm < 2; ++qm) { sfr[qm][0] = zf; sfr[qm][1] = zf; }

        if (t < 16) {
            #pragma unroll
            for (int kn = 0; kn < 2; ++kn)
                #pragma unroll
                for (int kc = 0; kc < 2; ++kc) {
                    s16x8 bk = *(const s16x8*)&qkv[(tokbase + t * 32 + kn * 16 + c) * 2304 + 768 + h * 64 + kc * 32 + g * 8];
                    #pragma unroll
                    for (int qm = 0; qm < 2; ++qm)
                        sfr[qm][kn] = MFMA16(qf[qm][kc], bk, sfr[qm][kn], 0, 0, 0);
                }
        } else {
            #pragma unroll
            for (int kc = 0; kc < 2; ++kc) {
                s16x8 bk = {0, 0, 0, 0, 0, 0, 0, 0};
                if (c == 0) bk = *(const s16x8*)&qkvc[b * 2304 + 768 + h * 64 + kc * 32 + g * 8];
                #pragma unroll
                for (int qm = 0; qm < 2; ++qm)
                    sfr[qm][0] = MFMA16(qf[qm][kc], bk, sfr[qm][0], 0, 0, 0);
            }
        }

        #pragma unroll
        for (int qm = 0; qm < 2; ++qm) {
            #pragma unroll
            for (int j = 0; j < 4; ++j) {
                float v0 = sfr[qm][0][j] * 0.125f;
                float v1 = (t < 16) ? sfr[qm][1][j] * 0.125f : -1e30f;
                if (t == 16 && c != 0) v0 = -1e30f;
                float tm = fmaxf(v0, v1);
                tm = fmaxf(tm, __shfl_xor(tm, 1));
                tm = fmaxf(tm, __shfl_xor(tm, 2));
                tm = fmaxf(tm, __shfl_xor(tm, 4));
                tm = fmaxf(tm, __shfl_xor(tm, 8));
                float mo = mst[qm][j];
                float mn = fmaxf(mo, tm);
                float scl = __expf(mo - mn);
                float p0 = __expf(v0 - mn);
                float p1 = __expf(v1 - mn);
                float ps = p0 + p1;
                ps += __shfl_xor(ps, 1); ps += __shfl_xor(ps, 2);
                ps += __shfl_xor(ps, 4); ps += __shfl_xor(ps, 8);
                lst[qm][j] = lst[qm][j] * scl + ps;
                mst[qm][j] = mn;
                #pragma unroll
                for (int dn = 0; dn < 4; ++dn) o[qm][dn][j] *= scl;
                int q = qm * 16 + g * 4 + j;
                Pl[w][q * 40 + c] = f2bf(p0);
                Pl[w][q * 40 + 16 + c] = f2bf(p1);
            }
        }

        // PV
        s16x8 pa[2], vb[4];
        #pragma unroll
        for (int qm = 0; qm < 2; ++qm) pa[qm] = *(const s16x8*)&Pl[w][(qm * 16 + c) * 40 + g * 8];
        #pragma unroll
        for (int dn = 0; dn < 4; ++dn) vb[dn] = *(const s16x8*)&Vt[(dn * 16 + c) * 40 + g * 8];
        #pragma unroll
        for (int qm = 0; qm < 2; ++qm)
            #pragma unroll
            for (int dn = 0; dn < 4; ++dn)
                o[qm][dn] = MFMA16(pa[qm], vb[dn], o[qm][dn], 0, 0, 0);
    }

    // scattered store (raw row-major reinterpretation layout)
    size_t ybase = (size_t)b * 1573632 + 768 + (size_t)nb * 393216 + (size_t)h * 32768;
    #pragma unroll
    for (int qm = 0; qm < 2; ++qm)
        #pragma unroll
        for (int dn = 0; dn < 4; ++dn)
            #pragma unroll
            for (int j = 0; j < 4; ++j) {
                int q = qbase + qm * 16 + g * 4 + j;
                int d = dn * 16 + c;
                y[ybase + (size_t)q * 64 + d] = f2bf(o[qm][dn][j] / lst[qm][j]);
            }
}

// ---------------- launch ----------------
extern "C" void kernel_launch(void* const* d_in, const int* in_sizes, int n_in,
                              void* d_out, int out_size, void* d_ws, size_t ws_size,
                              hipStream_t stream) {
    const float* x      = (const float*)d_in[0];
    const float* ln1_w  = (const float*)d_in[1];
    const float* ln1_b  = (const float*)d_in[2];
    const float* qkv_w  = (const float*)d_in[3];
    const float* proj_w = (const float*)d_in[4];
    const float* proj_b = (const float*)d_in[5];
    const float* ln2_w  = (const float*)d_in[6];
    const float* ln2_b  = (const float*)d_in[7];
    const float* fc1_w  = (const float*)d_in[8];
    const float* fc1_b  = (const float*)d_in[9];
    const float* fc2_w  = (const float*)d_in[10];
    const float* fc2_b  = (const float*)d_in[11];
    float* out = (float*)d_out;
    char* ws = (char*)d_ws;

    // ws layout (bytes); gbuf overlays [h1,qkv]; cls partials overlay x2 (temporally disjoint).
    u16* Wq   = (u16*)(ws + 0);
    u16* Wp   = (u16*)(ws + 3538944);
    u16* Wf1  = (u16*)(ws + 4718592);
    u16* Wf2  = (u16*)(ws + 9437184);
    u16* h1   = (u16*)(ws + 14155776);
    u16* qkv  = (u16*)(ws + 39333888);
    u16* yb   = (u16*)(ws + 114868224);
    float* x2 = (float*)(ws + 140046336);
    u16* h2   = (u16*)(ws + 190402560);
    u16* qkvc = (u16*)(ws + 215580672);
    u16* gbuf = (u16*)(ws + 14155776);   // overlay
    float* part = (float*)(ws + 140046336);  // overlay on x2 (free until proj gemm)

    cvt_kernel<<<1728, 256, 0, stream>>>(qkv_w, Wq, 1769472);
    cvt_kernel<<<576,  256, 0, stream>>>(proj_w, Wp, 589824);
    cvt_kernel<<<2304, 256, 0, stream>>>(fc1_w, Wf1, 2359296);
    cvt_kernel<<<2304, 256, 0, stream>>>(fc2_w, Wf2, 2359296);

    ln_kernel<<<16392, 256, 0, stream>>>(x, ln1_w, ln1_b, h1);
    gemm_bt<0><<<dim3(9, 65), 512, 0, stream>>>(h1, Wq, nullptr, nullptr, nullptr, qkv, 16392, 2304, 768);
    cls_part<<<1632, 256, 0, stream>>>(qkv, part);
    cls_red<<<96, 64, 0, stream>>>(part, h1, yb);
    qkvc_gemm<<<4608, 256, 0, stream>>>(yb, Wq, qkvc);
    battn<<<1536, 256, 0, stream>>>(qkv, qkvc, yb);
    gemm_bt<1><<<dim3(3, 65), 512, 0, stream>>>(yb, Wp, proj_b, x, x2, nullptr, 16392, 768, 768);
    ln_kernel<<<16392, 256, 0, stream>>>(x2, ln2_w, ln2_b, h2);
    gemm_bt<2><<<dim3(12, 65), 512, 0, stream>>>(h2, Wf1, fc1_b, nullptr, nullptr, gbuf, 16392, 3072, 768);
    gemm_bt<1><<<dim3(3, 65), 512, 0, stream>>>(gbuf, Wf2, fc2_b, x2, out, nullptr, 16392, 768, 3072);
}